// Round 1
// baseline (13161.766 us; speedup 1.0000x reference)
//
#include <hip/hip_runtime.h>
#include <math.h>

#define B_   16
#define N_   1025
#define C_   768
#define H_   12
#define HD   64
#define M_   (B_ * N_)      // 16400 rows
#define QKVN (3 * C_)       // 2304 cols

// ---------------------------------------------------------------------------
// Kernel 1: qkv = x @ W_qkv, scattered to q/k/v [B,H,N,hd] with RoPE fused in
// the epilogue. 64x64 tile, K-step 16, 256 threads, 4x4 microtile per thread.
// ---------------------------------------------------------------------------
__global__ __launch_bounds__(256) void qkv_gemm(
    const float* __restrict__ x,     // [M_, 768]
    const float* __restrict__ w,     // [768, 2304]
    const float* __restrict__ fcos,  // [1024, 32]
    const float* __restrict__ fsin,  // [1024, 32]
    float* __restrict__ q, float* __restrict__ k, float* __restrict__ v)
{
    __shared__ float As[16][65];   // [k][m], padded
    __shared__ float Bs[16][64];   // [k][n]

    const int tid = threadIdx.x;
    const int tx = tid & 15;       // col group
    const int ty = tid >> 4;       // row group
    const int n0 = blockIdx.x * 64;
    const int m0 = blockIdx.y * 64;

    const int arow = tid >> 2;         // 0..63
    const int acol = (tid & 3) * 4;    // 0,4,8,12
    const int brow = tid >> 4;         // 0..15
    const int bcol = (tid & 15) * 4;   // 0..60

    float acc[4][4] = {};

    for (int k0 = 0; k0 < 768; k0 += 16) {
        // A tile: 64 rows x 16 k
        const int am = m0 + arow;
        float4 a4 = make_float4(0.f, 0.f, 0.f, 0.f);
        if (am < M_) a4 = *(const float4*)(x + (size_t)am * 768 + k0 + acol);
        As[acol + 0][arow] = a4.x;
        As[acol + 1][arow] = a4.y;
        As[acol + 2][arow] = a4.z;
        As[acol + 3][arow] = a4.w;
        // B tile: 16 k x 64 cols
        float4 b4 = *(const float4*)(w + (size_t)(k0 + brow) * QKVN + n0 + bcol);
        *(float4*)(&Bs[brow][bcol]) = b4;
        __syncthreads();

        #pragma unroll
        for (int kk = 0; kk < 16; ++kk) {
            float ar[4], br[4];
            #pragma unroll
            for (int i = 0; i < 4; ++i) ar[i] = As[kk][ty * 4 + i];
            #pragma unroll
            for (int j = 0; j < 4; ++j) br[j] = Bs[kk][tx * 4 + j];
            #pragma unroll
            for (int i = 0; i < 4; ++i)
                #pragma unroll
                for (int j = 0; j < 4; ++j)
                    acc[i][j] += ar[i] * br[j];
        }
        __syncthreads();
    }

    // Epilogue: scatter with fused RoPE. Pairs (2p, 2p+1) are adjacent cols
    // inside this thread's 4-wide j-quad (tx*4+j even for j in {0,2}).
    #pragma unroll
    for (int i = 0; i < 4; ++i) {
        const int m = m0 + ty * 4 + i;
        if (m >= M_) continue;
        const int b   = m / N_;
        const int tok = m - b * N_;
        #pragma unroll
        for (int j = 0; j < 4; j += 2) {
            const int c = n0 + tx * 4 + j;
            const int which = c / C_;          // 0=q 1=k 2=v
            const int r = c - which * C_;
            const int h = r >> 6;
            const int d = r & 63;              // even
            float v0 = acc[i][j];
            float v1 = acc[i][j + 1];
            if (which < 2 && tok > 0) {
                const int p = d >> 1;
                const float cv = fcos[(size_t)(tok - 1) * 32 + p];
                const float sv = fsin[(size_t)(tok - 1) * 32 + p];
                const float nv0 = v0 * cv - v1 * sv;
                const float nv1 = v0 * sv + v1 * cv;
                v0 = nv0; v1 = nv1;
            }
            float* dst = (which == 0) ? q : (which == 1) ? k : v;
            const size_t off = (((size_t)b * H_ + h) * N_ + tok) * HD + d;
            dst[off]     = v0;
            dst[off + 1] = v1;
        }
    }
}

// ---------------------------------------------------------------------------
// Kernel 2: attention, one block (256 thr) per (b,h,query-row).
// Scores in LDS, block softmax, PV with coalesced V reads.
// Output overwrites the q row (only this block reads it).
// ---------------------------------------------------------------------------
__global__ __launch_bounds__(256) void attn_kernel(
    float* __restrict__ q,                 // [B*H, N, hd] (in: q, out: attn@V)
    const float* __restrict__ kbuf,        // [B*H, N, hd]
    const float* __restrict__ vbuf)        // [B*H, N, hd]
{
    const int idx = blockIdx.x;
    const int tok = idx % N_;
    const int bh  = idx / N_;

    float* qrow = q + ((size_t)bh * N_ + tok) * HD;
    const float* kb = kbuf + (size_t)bh * N_ * HD;
    const float* vb = vbuf + (size_t)bh * N_ * HD;

    __shared__ float qs[64];
    __shared__ float s[N_];
    __shared__ float red[8];
    __shared__ float ored[4][64];

    const int tid = threadIdx.x;
    if (tid < 16) {
        float4 t4 = ((const float4*)qrow)[tid];
        qs[tid * 4 + 0] = t4.x;
        qs[tid * 4 + 1] = t4.y;
        qs[tid * 4 + 2] = t4.z;
        qs[tid * 4 + 3] = t4.w;
    }
    __syncthreads();

    // scores: s[k] = scale * dot(q, K[k])
    const float scale = 0.125f;   // 64^-0.5
    for (int kk = tid; kk < N_; kk += 256) {
        const float* krow = kb + (size_t)kk * HD;
        float acc = 0.f;
        #pragma unroll
        for (int d = 0; d < 64; d += 4) {
            float4 k4 = *(const float4*)(krow + d);
            acc += qs[d] * k4.x + qs[d + 1] * k4.y
                 + qs[d + 2] * k4.z + qs[d + 3] * k4.w;
        }
        s[kk] = acc * scale;
    }
    __syncthreads();

    // block max
    float mx = -1e30f;
    for (int kk = tid; kk < N_; kk += 256) mx = fmaxf(mx, s[kk]);
    #pragma unroll
    for (int off = 32; off >= 1; off >>= 1) mx = fmaxf(mx, __shfl_xor(mx, off));
    const int wid = tid >> 6;
    if ((tid & 63) == 0) red[wid] = mx;
    __syncthreads();
    mx = fmaxf(fmaxf(red[0], red[1]), fmaxf(red[2], red[3]));

    // exp + block sum
    float sum = 0.f;
    for (int kk = tid; kk < N_; kk += 256) {
        float e = __expf(s[kk] - mx);
        s[kk] = e;
        sum += e;
    }
    #pragma unroll
    for (int off = 32; off >= 1; off >>= 1) sum += __shfl_xor(sum, off);
    if ((tid & 63) == 0) red[4 + wid] = sum;
    __syncthreads();
    sum = red[4] + red[5] + red[6] + red[7];
    const float rinv = 1.f / sum;

    // PV: lane owns d = tid&63, k-strip = tid>>6 (V reads coalesced per row)
    const int d  = tid & 63;
    const int kc = tid >> 6;
    float acc = 0.f;
    for (int kk = kc; kk < N_; kk += 4)
        acc += s[kk] * vb[(size_t)kk * HD + d];
    ored[kc][d] = acc;
    __syncthreads();
    if (tid < 64)
        qrow[tid] = (ored[0][tid] + ored[1][tid] + ored[2][tid] + ored[3][tid]) * rinv;
}

// ---------------------------------------------------------------------------
// Kernel 3: out = attn_out @ W_proj + bias. A gathered from [B,H,N,hd].
// ---------------------------------------------------------------------------
__global__ __launch_bounds__(256) void proj_gemm(
    const float* __restrict__ ao,     // attn out (q buffer), [B,H,N,hd]
    const float* __restrict__ w,      // [768, 768]
    const float* __restrict__ bias,   // [768]
    float* __restrict__ out)          // [M_, 768]
{
    __shared__ float As[16][65];
    __shared__ float Bs[16][64];

    const int tid = threadIdx.x;
    const int tx = tid & 15;
    const int ty = tid >> 4;
    const int n0 = blockIdx.x * 64;
    const int m0 = blockIdx.y * 64;

    const int arow = tid >> 2;
    const int acol = (tid & 3) * 4;
    const int brow = tid >> 4;
    const int bcol = (tid & 15) * 4;

    float acc[4][4] = {};

    for (int k0 = 0; k0 < 768; k0 += 16) {
        const int am = m0 + arow;
        float4 a4 = make_float4(0.f, 0.f, 0.f, 0.f);
        if (am < M_) {
            const int b   = am / N_;
            const int tok = am - b * N_;
            const int kk0 = k0 + acol;          // 4 consecutive, same head
            const int h = kk0 >> 6;
            const int d = kk0 & 63;
            a4 = *(const float4*)(ao + (((size_t)b * H_ + h) * N_ + tok) * HD + d);
        }
        As[acol + 0][arow] = a4.x;
        As[acol + 1][arow] = a4.y;
        As[acol + 2][arow] = a4.z;
        As[acol + 3][arow] = a4.w;
        float4 b4 = *(const float4*)(w + (size_t)(k0 + brow) * C_ + n0 + bcol);
        *(float4*)(&Bs[brow][bcol]) = b4;
        __syncthreads();

        #pragma unroll
        for (int kk = 0; kk < 16; ++kk) {
            float ar[4], br[4];
            #pragma unroll
            for (int i = 0; i < 4; ++i) ar[i] = As[kk][ty * 4 + i];
            #pragma unroll
            for (int j = 0; j < 4; ++j) br[j] = Bs[kk][tx * 4 + j];
            #pragma unroll
            for (int i = 0; i < 4; ++i)
                #pragma unroll
                for (int j = 0; j < 4; ++j)
                    acc[i][j] += ar[i] * br[j];
        }
        __syncthreads();
    }

    #pragma unroll
    for (int i = 0; i < 4; ++i) {
        const int m = m0 + ty * 4 + i;
        if (m >= M_) continue;
        #pragma unroll
        for (int j = 0; j < 4; ++j) {
            const int c = n0 + tx * 4 + j;
            out[(size_t)m * C_ + c] = acc[i][j] + bias[c];
        }
    }
}

// ---------------------------------------------------------------------------
extern "C" void kernel_launch(void* const* d_in, const int* in_sizes, int n_in,
                              void* d_out, int out_size, void* d_ws, size_t ws_size,
                              hipStream_t stream) {
    const float* x     = (const float*)d_in[0];
    const float* fcos  = (const float*)d_in[1];
    const float* fsin  = (const float*)d_in[2];
    const float* wqkv  = (const float*)d_in[3];
    const float* wproj = (const float*)d_in[4];
    const float* bproj = (const float*)d_in[5];
    float* out = (float*)d_out;

    const size_t QE = (size_t)B_ * H_ * N_ * HD;   // 12,595,200 elems
    float* q = (float*)d_ws;
    float* k = q + QE;
    float* v = k + QE;
    // ws needed: 3 * QE * 4 B = 151.2 MB

    dim3 g1(QKVN / 64, (M_ + 63) / 64);
    qkv_gemm<<<g1, 256, 0, stream>>>(x, wqkv, fcos, fsin, q, k, v);

    attn_kernel<<<dim3(B_ * H_ * N_), 256, 0, stream>>>(q, k, v);

    dim3 g2(C_ / 64, (M_ + 63) / 64);
    proj_gemm<<<g2, 256, 0, stream>>>(q, wproj, bproj, out);
}

// Round 8
// 2018.830 us; speedup vs baseline: 6.5195x; 6.5195x over previous
//
#include <hip/hip_runtime.h>
#include <math.h>

#define B_   16
#define N_   1025
#define C_   768
#define H_   12
#define HD   64
#define M_   (B_ * N_)      // 16400 rows
#define QKVN (3 * C_)       // 2304 cols
#define LDP  68             // LDS leading dim: mult of 4 (16B-aligned rows), bank-spread

// ---------------------------------------------------------------------------
// Kernel 1: qkv = x @ W_qkv, scattered to q/k/v [B,H,N,hd] with RoPE fused in
// the epilogue. 64x64 tile, K-step 16, 256 threads, 4x4 microtile per thread.
// ---------------------------------------------------------------------------
__global__ __launch_bounds__(256) void qkv_gemm(
    const float* __restrict__ x,     // [M_, 768]
    const float* __restrict__ w,     // [768, 2304]
    const float* __restrict__ fcos,  // [1024, 32]
    const float* __restrict__ fsin,  // [1024, 32]
    float* __restrict__ q, float* __restrict__ k, float* __restrict__ v)
{
    __shared__ float As[16][65];   // [k][m], padded
    __shared__ float Bs[16][64];   // [k][n]

    const int tid = threadIdx.x;
    const int tx = tid & 15;       // col group
    const int ty = tid >> 4;       // row group
    const int n0 = blockIdx.x * 64;
    const int m0 = blockIdx.y * 64;

    const int arow = tid >> 2;         // 0..63
    const int acol = (tid & 3) * 4;    // 0,4,8,12
    const int brow = tid >> 4;         // 0..15
    const int bcol = (tid & 15) * 4;   // 0..60

    float acc[4][4] = {};

    for (int k0 = 0; k0 < 768; k0 += 16) {
        const int am = m0 + arow;
        float4 a4 = make_float4(0.f, 0.f, 0.f, 0.f);
        if (am < M_) a4 = *(const float4*)(x + (size_t)am * 768 + k0 + acol);
        As[acol + 0][arow] = a4.x;
        As[acol + 1][arow] = a4.y;
        As[acol + 2][arow] = a4.z;
        As[acol + 3][arow] = a4.w;
        float4 b4 = *(const float4*)(w + (size_t)(k0 + brow) * QKVN + n0 + bcol);
        *(float4*)(&Bs[brow][bcol]) = b4;
        __syncthreads();

        #pragma unroll
        for (int kk = 0; kk < 16; ++kk) {
            float ar[4], br[4];
            #pragma unroll
            for (int i = 0; i < 4; ++i) ar[i] = As[kk][ty * 4 + i];
            #pragma unroll
            for (int j = 0; j < 4; ++j) br[j] = Bs[kk][tx * 4 + j];
            #pragma unroll
            for (int i = 0; i < 4; ++i)
                #pragma unroll
                for (int j = 0; j < 4; ++j)
                    acc[i][j] += ar[i] * br[j];
        }
        __syncthreads();
    }

    #pragma unroll
    for (int i = 0; i < 4; ++i) {
        const int m = m0 + ty * 4 + i;
        if (m >= M_) continue;
        const int b   = m / N_;
        const int tok = m - b * N_;
        #pragma unroll
        for (int j = 0; j < 4; j += 2) {
            const int c = n0 + tx * 4 + j;
            const int which = c / C_;          // 0=q 1=k 2=v
            const int r = c - which * C_;
            const int h = r >> 6;
            const int d = r & 63;              // even
            float v0 = acc[i][j];
            float v1 = acc[i][j + 1];
            if (which < 2 && tok > 0) {
                const int p = d >> 1;
                const float cv = fcos[(size_t)(tok - 1) * 32 + p];
                const float sv = fsin[(size_t)(tok - 1) * 32 + p];
                const float nv0 = v0 * cv - v1 * sv;
                const float nv1 = v0 * sv + v1 * cv;
                v0 = nv0; v1 = nv1;
            }
            float* dst = (which == 0) ? q : (which == 1) ? k : v;
            const size_t off = (((size_t)b * H_ + h) * N_ + tok) * HD + d;
            dst[off]     = v0;
            dst[off + 1] = v1;
        }
    }
}

// ---------------------------------------------------------------------------
// Kernel 2: flash-style attention. Block = (q-tile of 64 rows) x (b,h).
// S = Q K^T and O += P V as 64x64x64 fp32 GEMMs (4x4 microtile, b128 LDS
// operands), online softmax with per-row (m,l) via 16-lane shfl reductions.
// Pt aliases the Kt buffer (consumed before overwrite). Output overwrites q.
// ---------------------------------------------------------------------------
__global__ __launch_bounds__(256) void attn_flash(
    float* __restrict__ q,                 // [B*H, N, hd] in: q / out: attn@V
    const float* __restrict__ kbuf,        // [B*H, N, hd]
    const float* __restrict__ vbuf)        // [B*H, N, hd]
{
    __shared__ float Qt[64][LDP];   // [d][qrow], pre-scaled by 0.125
    __shared__ float KP[64][LDP];   // phase 1: Kt[d][kcol]; phase 2: Pt[kk][qrow]
    __shared__ float Vs[64][LDP];   // [kk][d]

    const int bh = blockIdx.y;
    const int q0 = blockIdx.x * 64;
    const int tid = threadIdx.x;
    const int tx = tid & 15;
    const int ty = tid >> 4;

    const float* kb = kbuf + (size_t)bh * N_ * HD;
    const float* vb = vbuf + (size_t)bh * N_ * HD;
    float* qb = q + (size_t)bh * N_ * HD;

    // Load Q tile transposed + scaled (once per block).
    {
        const int r  = tid >> 2;            // 0..63
        const int db = (tid & 3) * 16;      // 0,16,32,48
        int gr = q0 + r; if (gr >= N_) gr = N_ - 1;
        const float* src = qb + (size_t)gr * HD + db;
        #pragma unroll
        for (int u = 0; u < 4; ++u) {
            float4 t = *(const float4*)(src + u * 4);
            const int d = db + u * 4;
            Qt[d + 0][r] = t.x * 0.125f;
            Qt[d + 1][r] = t.y * 0.125f;
            Qt[d + 2][r] = t.z * 0.125f;
            Qt[d + 3][r] = t.w * 0.125f;
        }
    }

    float m[4], l[4], o[4][4];
    #pragma unroll
    for (int i = 0; i < 4; ++i) {
        m[i] = -1e30f; l[i] = 0.f;
        #pragma unroll
        for (int jj = 0; jj < 4; ++jj) o[i][jj] = 0.f;
    }

    const int nkt = (N_ + 63) / 64;   // 17
    for (int kt = 0; kt < nkt; ++kt) {
        const int k0 = kt * 64;
        __syncthreads();   // previous iter's Pt/Vs reads done (also covers Qt load)

        // Stage K (transposed) and V.
        {
            const int r  = tid >> 2;
            const int db = (tid & 3) * 16;
            int gr = k0 + r; if (gr >= N_) gr = N_ - 1;
            const float* ks = kb + (size_t)gr * HD + db;
            const float* vsrc = vb + (size_t)gr * HD + db;
            #pragma unroll
            for (int u = 0; u < 4; ++u) {
                float4 t = *(const float4*)(ks + u * 4);
                const int d = db + u * 4;
                KP[d + 0][r] = t.x;
                KP[d + 1][r] = t.y;
                KP[d + 2][r] = t.z;
                KP[d + 3][r] = t.w;
            }
            #pragma unroll
            for (int u = 0; u < 4; ++u)
                *(float4*)(&Vs[r][db + u * 4]) = *(const float4*)(vsrc + u * 4);
        }
        __syncthreads();

        // S = (Q*scale) K^T  (64x64x64, microtile 4x4, b128 operands)
        float s[4][4] = {{0.f}};
        #pragma unroll 8
        for (int d = 0; d < 64; ++d) {
            float4 a4 = *(const float4*)(&Qt[d][ty * 4]);
            float4 b4 = *(const float4*)(&KP[d][tx * 4]);
            float ar[4] = {a4.x, a4.y, a4.z, a4.w};
            float br[4] = {b4.x, b4.y, b4.z, b4.w};
            #pragma unroll
            for (int i = 0; i < 4; ++i)
                #pragma unroll
                for (int j = 0; j < 4; ++j)
                    s[i][j] += ar[i] * br[j];
        }

        // Online softmax update (row r = ty*4+i lives in the 16 lanes of tx).
        #pragma unroll
        for (int i = 0; i < 4; ++i) {
            float rm = -1e30f;
            #pragma unroll
            for (int j = 0; j < 4; ++j) {
                const int kcol = k0 + tx * 4 + j;
                if (kcol >= N_) s[i][j] = -1e30f;
                rm = fmaxf(rm, s[i][j]);
            }
            #pragma unroll
            for (int off = 1; off < 16; off <<= 1)
                rm = fmaxf(rm, __shfl_xor(rm, off));
            const float mn = fmaxf(m[i], rm);
            const float corr = __expf(m[i] - mn);
            m[i] = mn;
            float rs = 0.f;
            #pragma unroll
            for (int j = 0; j < 4; ++j) {
                const float p = __expf(s[i][j] - mn);
                s[i][j] = p;
                rs += p;
            }
            #pragma unroll
            for (int off = 1; off < 16; off <<= 1)
                rs += __shfl_xor(rs, off);
            l[i] = l[i] * corr + rs;
            #pragma unroll
            for (int jj = 0; jj < 4; ++jj) o[i][jj] *= corr;
        }

        __syncthreads();   // Kt fully consumed; safe to overwrite with Pt

        // Pt[kk][qrow] — i-direction (q rows) is contiguous -> b128 writes.
        #pragma unroll
        for (int j = 0; j < 4; ++j) {
            float4 pv = make_float4(s[0][j], s[1][j], s[2][j], s[3][j]);
            *(float4*)(&KP[tx * 4 + j][ty * 4]) = pv;
        }
        __syncthreads();

        // O += P V  (64x64x64, b128 operands)
        #pragma unroll 8
        for (int kk = 0; kk < 64; ++kk) {
            float4 a4 = *(const float4*)(&KP[kk][ty * 4]);   // P[ty*4+i][kk]
            float4 b4 = *(const float4*)(&Vs[kk][tx * 4]);   // V[kk][tx*4+jj]
            float ar[4] = {a4.x, a4.y, a4.z, a4.w};
            float br[4] = {b4.x, b4.y, b4.z, b4.w};
            #pragma unroll
            for (int i = 0; i < 4; ++i)
                #pragma unroll
                for (int jj = 0; jj < 4; ++jj)
                    o[i][jj] += ar[i] * br[jj];
        }
    }

    // Normalize and store (overwrite own q rows).
    #pragma unroll
    for (int i = 0; i < 4; ++i) {
        const int row = q0 + ty * 4 + i;
        if (row >= N_) continue;
        const float rinv = 1.f / l[i];
        float4 ov = make_float4(o[i][0] * rinv, o[i][1] * rinv,
                                o[i][2] * rinv, o[i][3] * rinv);
        *(float4*)(qb + (size_t)row * HD + tx * 4) = ov;
    }
}

// ---------------------------------------------------------------------------
// Kernel 3: out = attn_out @ W_proj + bias. A gathered from [B,H,N,hd].
// ---------------------------------------------------------------------------
__global__ __launch_bounds__(256) void proj_gemm(
    const float* __restrict__ ao,     // attn out (q buffer), [B,H,N,hd]
    const float* __restrict__ w,      // [768, 768]
    const float* __restrict__ bias,   // [768]
    float* __restrict__ out)          // [M_, 768]
{
    __shared__ float As[16][65];
    __shared__ float Bs[16][64];

    const int tid = threadIdx.x;
    const int tx = tid & 15;
    const int ty = tid >> 4;
    const int n0 = blockIdx.x * 64;
    const int m0 = blockIdx.y * 64;

    const int arow = tid >> 2;
    const int acol = (tid & 3) * 4;
    const int brow = tid >> 4;
    const int bcol = (tid & 15) * 4;

    float acc[4][4] = {};

    for (int k0 = 0; k0 < 768; k0 += 16) {
        const int am = m0 + arow;
        float4 a4 = make_float4(0.f, 0.f, 0.f, 0.f);
        if (am < M_) {
            const int b   = am / N_;
            const int tok = am - b * N_;
            const int kk0 = k0 + acol;          // 4 consecutive, same head
            const int h = kk0 >> 6;
            const int d = kk0 & 63;
            a4 = *(const float4*)(ao + (((size_t)b * H_ + h) * N_ + tok) * HD + d);
        }
        As[acol + 0][arow] = a4.x;
        As[acol + 1][arow] = a4.y;
        As[acol + 2][arow] = a4.z;
        As[acol + 3][arow] = a4.w;
        float4 b4 = *(const float4*)(w + (size_t)(k0 + brow) * C_ + n0 + bcol);
        *(float4*)(&Bs[brow][bcol]) = b4;
        __syncthreads();

        #pragma unroll
        for (int kk = 0; kk < 16; ++kk) {
            float ar[4], br[4];
            #pragma unroll
            for (int i = 0; i < 4; ++i) ar[i] = As[kk][ty * 4 + i];
            #pragma unroll
            for (int j = 0; j < 4; ++j) br[j] = Bs[kk][tx * 4 + j];
            #pragma unroll
            for (int i = 0; i < 4; ++i)
                #pragma unroll
                for (int j = 0; j < 4; ++j)
                    acc[i][j] += ar[i] * br[j];
        }
        __syncthreads();
    }

    #pragma unroll
    for (int i = 0; i < 4; ++i) {
        const int m = m0 + ty * 4 + i;
        if (m >= M_) continue;
        #pragma unroll
        for (int j = 0; j < 4; ++j) {
            const int c = n0 + tx * 4 + j;
            out[(size_t)m * C_ + c] = acc[i][j] + bias[c];
        }
    }
}

// ---------------------------------------------------------------------------
extern "C" void kernel_launch(void* const* d_in, const int* in_sizes, int n_in,
                              void* d_out, int out_size, void* d_ws, size_t ws_size,
                              hipStream_t stream) {
    const float* x     = (const float*)d_in[0];
    const float* fcos  = (const float*)d_in[1];
    const float* fsin  = (const float*)d_in[2];
    const float* wqkv  = (const float*)d_in[3];
    const float* wproj = (const float*)d_in[4];
    const float* bproj = (const float*)d_in[5];
    float* out = (float*)d_out;

    const size_t QE = (size_t)B_ * H_ * N_ * HD;   // 12,595,200 elems
    float* q = (float*)d_ws;
    float* k = q + QE;
    float* v = k + QE;
    // ws needed: 3 * QE * 4 B = 151.2 MB

    dim3 g1(QKVN / 64, (M_ + 63) / 64);
    qkv_gemm<<<g1, 256, 0, stream>>>(x, wqkv, fcos, fsin, q, k, v);

    attn_flash<<<dim3((N_ + 63) / 64, B_ * H_), 256, 0, stream>>>(q, k, v);

    dim3 g2(C_ / 64, (M_ + 63) / 64);
    proj_gemm<<<g2, 256, 0, stream>>>(q, wproj, bproj, out);
}

// Round 11
// 1246.977 us; speedup vs baseline: 10.5549x; 1.6190x over previous
//
#include <hip/hip_runtime.h>
#include <hip/hip_bf16.h>
#include <math.h>

#define B_   16
#define N_   1025
#define C_   768
#define H_   12
#define HD   64
#define M_   (B_ * N_)      // 16400 rows
#define QKVN (3 * C_)       // 2304 cols
#define LDP  68             // fp32 attn LDS leading dim
#define LDB  72             // bf16 GEMM LDS row stride (64 + 8 pad) -> conflict-free frag reads

typedef __attribute__((ext_vector_type(4))) float f32x4;
typedef __attribute__((ext_vector_type(8))) short s16x8;   // 8 bf16 = 4 VGPR

__device__ __forceinline__ unsigned short f2b(float f) {
    __hip_bfloat16 h = __float2bfloat16(f);   // RNE
    return *reinterpret_cast<unsigned short*>(&h);
}

// ---------------------------------------------------------------------------
// Kernel 1: qkv = x @ W_qkv via bf16 MFMA (fp32->bf16 fused in staging),
// RoPE fused in the epilogue, scattered to q/k/v [B,H,N,hd] fp32.
// 128x128 tile, BK=64, 4 waves, 4x4 frags of 16x16x32 per wave.
// ---------------------------------------------------------------------------
__global__ __launch_bounds__(256) void qkv_mfma(
    const float* __restrict__ x,     // [M_, 768]
    const float* __restrict__ w,     // [768, 2304]
    const float* __restrict__ fcos,  // [1024, 32]
    const float* __restrict__ fsin,  // [1024, 32]
    float* __restrict__ q, float* __restrict__ kout, float* __restrict__ v)
{
    __shared__ unsigned short Al[128][LDB];   // [m][k] bf16
    __shared__ unsigned short Bl[128][LDB];   // [n][k] bf16 (W transposed in staging)

    const int tid  = threadIdx.x;
    const int lane = tid & 63;
    const int wv   = tid >> 6;
    const int wr   = wv >> 1;         // wave row 0..1
    const int wc   = wv & 1;          // wave col 0..1
    const int n0   = blockIdx.x * 128;
    const int m0   = blockIdx.y * 128;

    f32x4 acc[4][4];
    #pragma unroll
    for (int i = 0; i < 4; ++i)
        #pragma unroll
        for (int j = 0; j < 4; ++j)
            acc[i][j] = (f32x4){0.f, 0.f, 0.f, 0.f};

    for (int kt = 0; kt < 768 / 64; ++kt) {
        const int k0 = kt * 64;
        __syncthreads();   // previous iter's frag reads done

        // ---- stage A: x[m0..+127][k0..+63] fp32 -> bf16 (b64 writes, 2-way max)
        {
            const int row = tid >> 2;            // 0..63
            const int cf4 = tid & 3;             // +4u -> float4 col
            #pragma unroll
            for (int h = 0; h < 2; ++h) {
                const int rr = row + 64 * h;
                int gm = m0 + rr; if (gm >= M_) gm = M_ - 1;
                const float* src = x + (size_t)gm * 768 + k0;
                #pragma unroll
                for (int u = 0; u < 4; ++u) {
                    const int f4 = cf4 + 4 * u;
                    float4 t = *(const float4*)(src + f4 * 4);
                    uint2 pk;
                    pk.x = (unsigned)f2b(t.x) | ((unsigned)f2b(t.y) << 16);
                    pk.y = (unsigned)f2b(t.z) | ((unsigned)f2b(t.w) << 16);
                    *reinterpret_cast<uint2*>(&Al[rr][f4 * 4]) = pk;
                }
            }
        }
        // ---- stage B: w[k0..+63][n0..+127] fp32 -> Bl[n][k] bf16 (ushort2 pairs)
        {
            const int kp = tid >> 3;             // 0..31 -> k rows 2kp, 2kp+1
            const int nb = tid & 7;              // +8v -> float4 col
            const float* src = w + (size_t)(k0 + 2 * kp) * QKVN + n0;
            #pragma unroll
            for (int vv = 0; vv < 4; ++vv) {
                const int f4 = nb + 8 * vv;
                float4 t0 = *(const float4*)(src + f4 * 4);
                float4 t1 = *(const float4*)(src + QKVN + f4 * 4);
                #pragma unroll
                for (int c = 0; c < 4; ++c) {
                    unsigned int pr = (unsigned)f2b((&t0.x)[c])
                                    | ((unsigned)f2b((&t1.x)[c]) << 16);
                    *reinterpret_cast<unsigned int*>(&Bl[f4 * 4 + c][2 * kp]) = pr;
                }
            }
        }
        __syncthreads();

        // ---- MFMA: 2 k-steps of 32
        #pragma unroll
        for (int ks = 0; ks < 2; ++ks) {
            const int kb = ks * 32 + (lane >> 4) * 8;
            s16x8 af[4], bf[4];
            #pragma unroll
            for (int fi = 0; fi < 4; ++fi)
                af[fi] = *reinterpret_cast<const s16x8*>(&Al[wr * 64 + fi * 16 + (lane & 15)][kb]);
            #pragma unroll
            for (int fj = 0; fj < 4; ++fj)
                bf[fj] = *reinterpret_cast<const s16x8*>(&Bl[wc * 64 + fj * 16 + (lane & 15)][kb]);
            #pragma unroll
            for (int fi = 0; fi < 4; ++fi)
                #pragma unroll
                for (int fj = 0; fj < 4; ++fj)
                    acc[fi][fj] = __builtin_amdgcn_mfma_f32_16x16x32_bf16(
                        af[fi], bf[fj], acc[fi][fj], 0, 0, 0);
        }
    }

    // ---- epilogue: RoPE (pairs = adjacent lanes) + scatter to q/k/v
    #pragma unroll
    for (int fj = 0; fj < 4; ++fj) {
        const int gn = n0 + wc * 64 + fj * 16 + (lane & 15);
        const int which = gn / C_;               // 0=q 1=k 2=v
        const int rr = gn - which * C_;
        const int hh = rr >> 6;
        const int d  = rr & 63;
        const int p  = d >> 1;
        float* dst = (which == 0) ? q : (which == 1) ? kout : v;
        #pragma unroll
        for (int fi = 0; fi < 4; ++fi) {
            #pragma unroll
            for (int r = 0; r < 4; ++r) {
                const int gm = m0 + wr * 64 + fi * 16 + (lane >> 4) * 4 + r;
                float val = acc[fi][fj][r];
                float partner = __shfl_xor(val, 1);   // all lanes execute
                if (gm < M_) {
                    const int b   = gm / N_;
                    const int tok = gm - b * N_;
                    float outv = val;
                    if (which < 2 && tok > 0) {
                        const float cv = fcos[(size_t)(tok - 1) * 32 + p];
                        const float sv = fsin[(size_t)(tok - 1) * 32 + p];
                        outv = (lane & 1) ? (partner * sv + val * cv)
                                          : (val * cv - partner * sv);
                    }
                    dst[(((size_t)b * H_ + hh) * N_ + tok) * HD + d] = outv;
                }
            }
        }
    }
}

// ---------------------------------------------------------------------------
// Kernel 2: flash-style attention (UNCHANGED from validated Round-8 kernel).
// ---------------------------------------------------------------------------
__global__ __launch_bounds__(256) void attn_flash(
    float* __restrict__ q,                 // [B*H, N, hd] in: q / out: attn@V
    const float* __restrict__ kbuf,        // [B*H, N, hd]
    const float* __restrict__ vbuf)        // [B*H, N, hd]
{
    __shared__ float Qt[64][LDP];   // [d][qrow], pre-scaled by 0.125
    __shared__ float KP[64][LDP];   // phase 1: Kt[d][kcol]; phase 2: Pt[kk][qrow]
    __shared__ float Vs[64][LDP];   // [kk][d]

    const int bh = blockIdx.y;
    const int q0 = blockIdx.x * 64;
    const int tid = threadIdx.x;
    const int tx = tid & 15;
    const int ty = tid >> 4;

    const float* kb = kbuf + (size_t)bh * N_ * HD;
    const float* vb = vbuf + (size_t)bh * N_ * HD;
    float* qb = q + (size_t)bh * N_ * HD;

    {
        const int r  = tid >> 2;
        const int db = (tid & 3) * 16;
        int gr = q0 + r; if (gr >= N_) gr = N_ - 1;
        const float* src = qb + (size_t)gr * HD + db;
        #pragma unroll
        for (int u = 0; u < 4; ++u) {
            float4 t = *(const float4*)(src + u * 4);
            const int d = db + u * 4;
            Qt[d + 0][r] = t.x * 0.125f;
            Qt[d + 1][r] = t.y * 0.125f;
            Qt[d + 2][r] = t.z * 0.125f;
            Qt[d + 3][r] = t.w * 0.125f;
        }
    }

    float m[4], l[4], o[4][4];
    #pragma unroll
    for (int i = 0; i < 4; ++i) {
        m[i] = -1e30f; l[i] = 0.f;
        #pragma unroll
        for (int jj = 0; jj < 4; ++jj) o[i][jj] = 0.f;
    }

    const int nkt = (N_ + 63) / 64;   // 17
    for (int kt = 0; kt < nkt; ++kt) {
        const int k0 = kt * 64;
        __syncthreads();

        {
            const int r  = tid >> 2;
            const int db = (tid & 3) * 16;
            int gr = k0 + r; if (gr >= N_) gr = N_ - 1;
            const float* ks = kb + (size_t)gr * HD + db;
            const float* vsrc = vb + (size_t)gr * HD + db;
            #pragma unroll
            for (int u = 0; u < 4; ++u) {
                float4 t = *(const float4*)(ks + u * 4);
                const int d = db + u * 4;
                KP[d + 0][r] = t.x;
                KP[d + 1][r] = t.y;
                KP[d + 2][r] = t.z;
                KP[d + 3][r] = t.w;
            }
            #pragma unroll
            for (int u = 0; u < 4; ++u)
                *(float4*)(&Vs[r][db + u * 4]) = *(const float4*)(vsrc + u * 4);
        }
        __syncthreads();

        float s[4][4] = {{0.f}};
        #pragma unroll 8
        for (int d = 0; d < 64; ++d) {
            float4 a4 = *(const float4*)(&Qt[d][ty * 4]);
            float4 b4 = *(const float4*)(&KP[d][tx * 4]);
            float ar[4] = {a4.x, a4.y, a4.z, a4.w};
            float br[4] = {b4.x, b4.y, b4.z, b4.w};
            #pragma unroll
            for (int i = 0; i < 4; ++i)
                #pragma unroll
                for (int j = 0; j < 4; ++j)
                    s[i][j] += ar[i] * br[j];
        }

        #pragma unroll
        for (int i = 0; i < 4; ++i) {
            float rm = -1e30f;
            #pragma unroll
            for (int j = 0; j < 4; ++j) {
                const int kcol = k0 + tx * 4 + j;
                if (kcol >= N_) s[i][j] = -1e30f;
                rm = fmaxf(rm, s[i][j]);
            }
            #pragma unroll
            for (int off = 1; off < 16; off <<= 1)
                rm = fmaxf(rm, __shfl_xor(rm, off));
            const float mn = fmaxf(m[i], rm);
            const float corr = __expf(m[i] - mn);
            m[i] = mn;
            float rs = 0.f;
            #pragma unroll
            for (int j = 0; j < 4; ++j) {
                const float p = __expf(s[i][j] - mn);
                s[i][j] = p;
                rs += p;
            }
            #pragma unroll
            for (int off = 1; off < 16; off <<= 1)
                rs += __shfl_xor(rs, off);
            l[i] = l[i] * corr + rs;
            #pragma unroll
            for (int jj = 0; jj < 4; ++jj) o[i][jj] *= corr;
        }

        __syncthreads();

        #pragma unroll
        for (int j = 0; j < 4; ++j) {
            float4 pv = make_float4(s[0][j], s[1][j], s[2][j], s[3][j]);
            *(float4*)(&KP[tx * 4 + j][ty * 4]) = pv;
        }
        __syncthreads();

        #pragma unroll 8
        for (int kk = 0; kk < 64; ++kk) {
            float4 a4 = *(const float4*)(&KP[kk][ty * 4]);
            float4 b4 = *(const float4*)(&Vs[kk][tx * 4]);
            float ar[4] = {a4.x, a4.y, a4.z, a4.w};
            float br[4] = {b4.x, b4.y, b4.z, b4.w};
            #pragma unroll
            for (int i = 0; i < 4; ++i)
                #pragma unroll
                for (int jj = 0; jj < 4; ++jj)
                    o[i][jj] += ar[i] * br[jj];
        }
    }

    #pragma unroll
    for (int i = 0; i < 4; ++i) {
        const int row = q0 + ty * 4 + i;
        if (row >= N_) continue;
        const float rinv = 1.f / l[i];
        float4 ov = make_float4(o[i][0] * rinv, o[i][1] * rinv,
                                o[i][2] * rinv, o[i][3] * rinv);
        *(float4*)(qb + (size_t)row * HD + tx * 4) = ov;
    }
}

// ---------------------------------------------------------------------------
// Kernel 3: out = attn_out @ W_proj + bias via bf16 MFMA.
// A gathered from [B,H,N,hd] in staging (BK=64 => one head per K-tile).
// ---------------------------------------------------------------------------
__global__ __launch_bounds__(256) void proj_mfma(
    const float* __restrict__ ao,     // attn out (q buffer), [B,H,N,hd]
    const float* __restrict__ w,      // [768, 768]
    const float* __restrict__ bias,   // [768]
    float* __restrict__ out)          // [M_, 768]
{
    __shared__ unsigned short Al[128][LDB];
    __shared__ unsigned short Bl[128][LDB];

    const int tid  = threadIdx.x;
    const int lane = tid & 63;
    const int wv   = tid >> 6;
    const int wr   = wv >> 1;
    const int wc   = wv & 1;
    const int n0   = blockIdx.x * 128;
    const int m0   = blockIdx.y * 128;

    f32x4 acc[4][4];
    #pragma unroll
    for (int i = 0; i < 4; ++i)
        #pragma unroll
        for (int j = 0; j < 4; ++j)
            acc[i][j] = (f32x4){0.f, 0.f, 0.f, 0.f};

    for (int kt = 0; kt < H_; ++kt) {       // 12 K-tiles = 12 heads
        const int k0 = kt * 64;
        __syncthreads();

        // ---- stage A: gathered head kt, fp32 -> bf16
        {
            const int row = tid >> 2;
            const int cf4 = tid & 3;
            #pragma unroll
            for (int h2 = 0; h2 < 2; ++h2) {
                const int rr = row + 64 * h2;
                int gm = m0 + rr; if (gm >= M_) gm = M_ - 1;
                const int b   = gm / N_;
                const int tok = gm - b * N_;
                const float* src = ao + (((size_t)b * H_ + kt) * N_ + tok) * HD;
                #pragma unroll
                for (int u = 0; u < 4; ++u) {
                    const int f4 = cf4 + 4 * u;
                    float4 t = *(const float4*)(src + f4 * 4);
                    uint2 pk;
                    pk.x = (unsigned)f2b(t.x) | ((unsigned)f2b(t.y) << 16);
                    pk.y = (unsigned)f2b(t.z) | ((unsigned)f2b(t.w) << 16);
                    *reinterpret_cast<uint2*>(&Al[rr][f4 * 4]) = pk;
                }
            }
        }
        // ---- stage B: w[k0..+63][n0..+127] -> Bl[n][k]
        {
            const int kp = tid >> 3;
            const int nb = tid & 7;
            const float* src = w + (size_t)(k0 + 2 * kp) * C_ + n0;
            #pragma unroll
            for (int vv = 0; vv < 4; ++vv) {
                const int f4 = nb + 8 * vv;
                float4 t0 = *(const float4*)(src + f4 * 4);
                float4 t1 = *(const float4*)(src + C_ + f4 * 4);
                #pragma unroll
                for (int c = 0; c < 4; ++c) {
                    unsigned int pr = (unsigned)f2b((&t0.x)[c])
                                    | ((unsigned)f2b((&t1.x)[c]) << 16);
                    *reinterpret_cast<unsigned int*>(&Bl[f4 * 4 + c][2 * kp]) = pr;
                }
            }
        }
        __syncthreads();

        #pragma unroll
        for (int ks = 0; ks < 2; ++ks) {
            const int kb = ks * 32 + (lane >> 4) * 8;
            s16x8 af[4], bf[4];
            #pragma unroll
            for (int fi = 0; fi < 4; ++fi)
                af[fi] = *reinterpret_cast<const s16x8*>(&Al[wr * 64 + fi * 16 + (lane & 15)][kb]);
            #pragma unroll
            for (int fj = 0; fj < 4; ++fj)
                bf[fj] = *reinterpret_cast<const s16x8*>(&Bl[wc * 64 + fj * 16 + (lane & 15)][kb]);
            #pragma unroll
            for (int fi = 0; fi < 4; ++fi)
                #pragma unroll
                for (int fj = 0; fj < 4; ++fj)
                    acc[fi][fj] = __builtin_amdgcn_mfma_f32_16x16x32_bf16(
                        af[fi], bf[fj], acc[fi][fj], 0, 0, 0);
        }
    }

    #pragma unroll
    for (int fj = 0; fj < 4; ++fj) {
        const int gn = n0 + wc * 64 + fj * 16 + (lane & 15);
        const float bv = bias[gn];
        #pragma unroll
        for (int fi = 0; fi < 4; ++fi) {
            #pragma unroll
            for (int r = 0; r < 4; ++r) {
                const int gm = m0 + wr * 64 + fi * 16 + (lane >> 4) * 4 + r;
                if (gm < M_) out[(size_t)gm * C_ + gn] = acc[fi][fj][r] + bv;
            }
        }
    }
}

// ---------------------------------------------------------------------------
extern "C" void kernel_launch(void* const* d_in, const int* in_sizes, int n_in,
                              void* d_out, int out_size, void* d_ws, size_t ws_size,
                              hipStream_t stream) {
    const float* x     = (const float*)d_in[0];
    const float* fcos  = (const float*)d_in[1];
    const float* fsin  = (const float*)d_in[2];
    const float* wqkv  = (const float*)d_in[3];
    const float* wproj = (const float*)d_in[4];
    const float* bproj = (const float*)d_in[5];
    float* out = (float*)d_out;

    const size_t QE = (size_t)B_ * H_ * N_ * HD;   // 12,595,200 elems
    float* q = (float*)d_ws;
    float* k = q + QE;
    float* v = k + QE;
    // ws needed: 3 * QE * 4 B = 151.2 MB (unchanged from validated round)

    qkv_mfma<<<dim3(QKVN / 128, (M_ + 127) / 128), 256, 0, stream>>>(
        x, wqkv, fcos, fsin, q, k, v);

    attn_flash<<<dim3((N_ + 63) / 64, B_ * H_), 256, 0, stream>>>(q, k, v);

    proj_mfma<<<dim3(C_ / 128, (M_ + 127) / 128), 256, 0, stream>>>(
        q, wproj, bproj, out);
}

// Round 13
// 656.114 us; speedup vs baseline: 20.0602x; 1.9005x over previous
//
#include <hip/hip_runtime.h>
#include <hip/hip_bf16.h>
#include <math.h>

#define B_   16
#define N_   1025
#define C_   768
#define H_   12
#define HD   64
#define M_   (B_ * N_)      // 16400 rows
#define QKVN (3 * C_)       // 2304 cols
#define LDB  72             // bf16 LDS row stride (ushorts): 144B rows, 16B-aligned, bank-spread

typedef __attribute__((ext_vector_type(4))) float f32x4;
typedef __attribute__((ext_vector_type(8))) short s16x8;   // 8 bf16 = 4 VGPR

__device__ __forceinline__ unsigned short f2b(float f) {
    __hip_bfloat16 h = __float2bfloat16(f);   // RNE
    return *reinterpret_cast<unsigned short*>(&h);
}

// ---------------------------------------------------------------------------
// Kernel 1: qkv = x @ W_qkv via bf16 MFMA (UNCHANGED from validated R11).
// ---------------------------------------------------------------------------
__global__ __launch_bounds__(256) void qkv_mfma(
    const float* __restrict__ x,     // [M_, 768]
    const float* __restrict__ w,     // [768, 2304]
    const float* __restrict__ fcos,  // [1024, 32]
    const float* __restrict__ fsin,  // [1024, 32]
    float* __restrict__ q, float* __restrict__ kout, float* __restrict__ v)
{
    __shared__ unsigned short Al[128][LDB];   // [m][k] bf16
    __shared__ unsigned short Bl[128][LDB];   // [n][k] bf16 (W transposed in staging)

    const int tid  = threadIdx.x;
    const int lane = tid & 63;
    const int wv   = tid >> 6;
    const int wr   = wv >> 1;         // wave row 0..1
    const int wc   = wv & 1;          // wave col 0..1
    const int n0   = blockIdx.x * 128;
    const int m0   = blockIdx.y * 128;

    f32x4 acc[4][4];
    #pragma unroll
    for (int i = 0; i < 4; ++i)
        #pragma unroll
        for (int j = 0; j < 4; ++j)
            acc[i][j] = (f32x4){0.f, 0.f, 0.f, 0.f};

    for (int kt = 0; kt < 768 / 64; ++kt) {
        const int k0 = kt * 64;
        __syncthreads();   // previous iter's frag reads done

        // ---- stage A: x[m0..+127][k0..+63] fp32 -> bf16
        {
            const int row = tid >> 2;            // 0..63
            const int cf4 = tid & 3;             // +4u -> float4 col
            #pragma unroll
            for (int h = 0; h < 2; ++h) {
                const int rr = row + 64 * h;
                int gm = m0 + rr; if (gm >= M_) gm = M_ - 1;
                const float* src = x + (size_t)gm * 768 + k0;
                #pragma unroll
                for (int u = 0; u < 4; ++u) {
                    const int f4 = cf4 + 4 * u;
                    float4 t = *(const float4*)(src + f4 * 4);
                    uint2 pk;
                    pk.x = (unsigned)f2b(t.x) | ((unsigned)f2b(t.y) << 16);
                    pk.y = (unsigned)f2b(t.z) | ((unsigned)f2b(t.w) << 16);
                    *reinterpret_cast<uint2*>(&Al[rr][f4 * 4]) = pk;
                }
            }
        }
        // ---- stage B: w[k0..+63][n0..+127] fp32 -> Bl[n][k] bf16
        {
            const int kp = tid >> 3;             // 0..31 -> k rows 2kp, 2kp+1
            const int nb = tid & 7;              // +8v -> float4 col
            const float* src = w + (size_t)(k0 + 2 * kp) * QKVN + n0;
            #pragma unroll
            for (int vv = 0; vv < 4; ++vv) {
                const int f4 = nb + 8 * vv;
                float4 t0 = *(const float4*)(src + f4 * 4);
                float4 t1 = *(const float4*)(src + QKVN + f4 * 4);
                #pragma unroll
                for (int c = 0; c < 4; ++c) {
                    unsigned int pr = (unsigned)f2b((&t0.x)[c])
                                    | ((unsigned)f2b((&t1.x)[c]) << 16);
                    *reinterpret_cast<unsigned int*>(&Bl[f4 * 4 + c][2 * kp]) = pr;
                }
            }
        }
        __syncthreads();

        #pragma unroll
        for (int ks = 0; ks < 2; ++ks) {
            const int kb = ks * 32 + (lane >> 4) * 8;
            s16x8 af[4], bf[4];
            #pragma unroll
            for (int fi = 0; fi < 4; ++fi)
                af[fi] = *reinterpret_cast<const s16x8*>(&Al[wr * 64 + fi * 16 + (lane & 15)][kb]);
            #pragma unroll
            for (int fj = 0; fj < 4; ++fj)
                bf[fj] = *reinterpret_cast<const s16x8*>(&Bl[wc * 64 + fj * 16 + (lane & 15)][kb]);
            #pragma unroll
            for (int fi = 0; fi < 4; ++fi)
                #pragma unroll
                for (int fj = 0; fj < 4; ++fj)
                    acc[fi][fj] = __builtin_amdgcn_mfma_f32_16x16x32_bf16(
                        af[fi], bf[fj], acc[fi][fj], 0, 0, 0);
        }
    }

    // ---- epilogue: RoPE (pairs = adjacent lanes) + scatter to q/k/v
    #pragma unroll
    for (int fj = 0; fj < 4; ++fj) {
        const int gn = n0 + wc * 64 + fj * 16 + (lane & 15);
        const int which = gn / C_;               // 0=q 1=k 2=v
        const int rr = gn - which * C_;
        const int hh = rr >> 6;
        const int d  = rr & 63;
        const int p  = d >> 1;
        float* dst = (which == 0) ? q : (which == 1) ? kout : v;
        #pragma unroll
        for (int fi = 0; fi < 4; ++fi) {
            #pragma unroll
            for (int r = 0; r < 4; ++r) {
                const int gm = m0 + wr * 64 + fi * 16 + (lane >> 4) * 4 + r;
                float val = acc[fi][fj][r];
                float partner = __shfl_xor(val, 1);   // all lanes execute
                if (gm < M_) {
                    const int b   = gm / N_;
                    const int tok = gm - b * N_;
                    float outv = val;
                    if (which < 2 && tok > 0) {
                        const float cv = fcos[(size_t)(tok - 1) * 32 + p];
                        const float sv = fsin[(size_t)(tok - 1) * 32 + p];
                        outv = (lane & 1) ? (partner * sv + val * cv)
                                          : (val * cv - partner * sv);
                    }
                    dst[(((size_t)b * H_ + hh) * N_ + tok) * HD + d] = outv;
                }
            }
        }
    }
}

// ---------------------------------------------------------------------------
// Kernel 2: flash attention via bf16 MFMA. Block = 64 q-rows x (b,h), 4 waves.
// Wave owns 16 q-rows. QK^T: A=Qs[q][d], B=Ks[tok][d] (both natural row-major
// bf16, proven frag pattern). S D-layout: tok=lane&15, q=(lane>>4)*4+reg ->
// row softmax via shfl over the 16 tok-lanes. P staged to Ps[q][tok] bf16
// (wave-private rows, no barrier). PV: A=Ps frag, B=Vt[d][tok] frag.
// ---------------------------------------------------------------------------
__global__ __launch_bounds__(256) void attn_mfma(
    float* __restrict__ q,                 // [B*H, N, hd] in: q / out: attn@V
    const float* __restrict__ kbuf,        // [B*H, N, hd]
    const float* __restrict__ vbuf)        // [B*H, N, hd]
{
    __shared__ unsigned short Qs[64][LDB];   // [q][d], pre-scaled by 0.125
    __shared__ unsigned short Ks[64][LDB];   // [tok][d]
    __shared__ unsigned short Vt[64][LDB];   // [d][tok]
    __shared__ unsigned short Ps[64][LDB];   // [q][tok]

    const int bh  = blockIdx.y;
    const int q0  = blockIdx.x * 64;
    const int tid = threadIdx.x;
    const int lane = tid & 63;
    const int wv  = tid >> 6;        // wave 0..3 -> q-rows 16wv..16wv+15
    const int c   = lane & 15;
    const int g   = lane >> 4;

    const float* kb = kbuf + (size_t)bh * N_ * HD;
    const float* vb = vbuf + (size_t)bh * N_ * HD;
    float* qb = q + (size_t)bh * N_ * HD;

    // ---- stage Qs once: [q][d] bf16, scaled by 0.125
    {
        const int row = tid >> 2;
        const int cf4 = tid & 3;
        int gr = q0 + row; if (gr >= N_) gr = N_ - 1;
        const float* src = qb + (size_t)gr * HD;
        #pragma unroll
        for (int u = 0; u < 4; ++u) {
            const int f4 = cf4 + 4 * u;
            float4 t = *(const float4*)(src + f4 * 4);
            uint2 pk;
            pk.x = (unsigned)f2b(t.x * 0.125f) | ((unsigned)f2b(t.y * 0.125f) << 16);
            pk.y = (unsigned)f2b(t.z * 0.125f) | ((unsigned)f2b(t.w * 0.125f) << 16);
            *reinterpret_cast<uint2*>(&Qs[row][f4 * 4]) = pk;
        }
    }

    float m[4], l[4];
    f32x4 o[4];
    #pragma unroll
    for (int r = 0; r < 4; ++r) { m[r] = -1e30f; l[r] = 0.f; }
    #pragma unroll
    for (int fd = 0; fd < 4; ++fd) o[fd] = (f32x4){0.f, 0.f, 0.f, 0.f};

    const int nkt = (N_ + 63) / 64;   // 17
    for (int kt = 0; kt < nkt; ++kt) {
        const int k0 = kt * 64;
        __syncthreads();   // prev tile's Ks/Vt reads done (covers Qs on iter 0)

        // ---- stage Ks: [tok][d] bf16 (straight copy)
        {
            const int row = tid >> 2;
            const int cf4 = tid & 3;
            int gr = k0 + row; if (gr >= N_) gr = N_ - 1;
            const float* src = kb + (size_t)gr * HD;
            #pragma unroll
            for (int u = 0; u < 4; ++u) {
                const int f4 = cf4 + 4 * u;
                float4 t = *(const float4*)(src + f4 * 4);
                uint2 pk;
                pk.x = (unsigned)f2b(t.x) | ((unsigned)f2b(t.y) << 16);
                pk.y = (unsigned)f2b(t.z) | ((unsigned)f2b(t.w) << 16);
                *reinterpret_cast<uint2*>(&Ks[row][f4 * 4]) = pk;
            }
        }
        // ---- stage Vt: [d][tok] bf16 (transposed, proven B-staging pattern)
        {
            const int kp = tid >> 3;             // 0..31 -> tokens 2kp, 2kp+1
            const int nb = tid & 7;              // d float4 selector
            int gr0 = k0 + 2 * kp;     if (gr0 >= N_) gr0 = N_ - 1;
            int gr1 = k0 + 2 * kp + 1; if (gr1 >= N_) gr1 = N_ - 1;
            const float* s0 = vb + (size_t)gr0 * HD;
            const float* s1 = vb + (size_t)gr1 * HD;
            #pragma unroll
            for (int vv2 = 0; vv2 < 2; ++vv2) {
                const int f4 = nb + 8 * vv2;
                float4 t0 = *(const float4*)(s0 + f4 * 4);
                float4 t1 = *(const float4*)(s1 + f4 * 4);
                #pragma unroll
                for (int cc = 0; cc < 4; ++cc) {
                    unsigned int pr = (unsigned)f2b((&t0.x)[cc])
                                    | ((unsigned)f2b((&t1.x)[cc]) << 16);
                    *reinterpret_cast<unsigned int*>(&Vt[f4 * 4 + cc][2 * kp]) = pr;
                }
            }
        }
        __syncthreads();

        // ---- S = Q K^T : A = Qs rows 16wv.., B = Ks token blocks
        f32x4 s[4];
        #pragma unroll
        for (int ft = 0; ft < 4; ++ft) s[ft] = (f32x4){0.f, 0.f, 0.f, 0.f};
        #pragma unroll
        for (int ks = 0; ks < 2; ++ks) {
            const int kb2 = ks * 32 + g * 8;
            s16x8 aq = *reinterpret_cast<const s16x8*>(&Qs[16 * wv + c][kb2]);
            #pragma unroll
            for (int ft = 0; ft < 4; ++ft) {
                s16x8 bk = *reinterpret_cast<const s16x8*>(&Ks[16 * ft + c][kb2]);
                s[ft] = __builtin_amdgcn_mfma_f32_16x16x32_bf16(aq, bk, s[ft], 0, 0, 0);
            }
        }

        // ---- mask OOB tokens (token = k0 + 16ft + c, same for all 4 regs)
        #pragma unroll
        for (int ft = 0; ft < 4; ++ft)
            if (k0 + 16 * ft + c >= N_)
                s[ft] = (f32x4){-1e30f, -1e30f, -1e30f, -1e30f};

        // ---- online softmax (row q = 16wv + 4g + r; reduce over 16 c-lanes)
        #pragma unroll
        for (int r = 0; r < 4; ++r) {
            float rm = fmaxf(fmaxf(s[0][r], s[1][r]), fmaxf(s[2][r], s[3][r]));
            #pragma unroll
            for (int off = 1; off < 16; off <<= 1)
                rm = fmaxf(rm, __shfl_xor(rm, off));
            const float mn = fmaxf(m[r], rm);
            const float corr = __expf(m[r] - mn);
            m[r] = mn;
            float rs = 0.f;
            #pragma unroll
            for (int ft = 0; ft < 4; ++ft) {
                float p = __expf(s[ft][r] - mn);
                s[ft][r] = p;
                rs += p;
            }
            #pragma unroll
            for (int off = 1; off < 16; off <<= 1)
                rs += __shfl_xor(rs, off);
            l[r] = l[r] * corr + rs;
            #pragma unroll
            for (int fd = 0; fd < 4; ++fd) o[fd][r] *= corr;
        }

        // ---- P -> Ps[q][tok] bf16 (wave-private rows; same-wave read next)
        #pragma unroll
        for (int ft = 0; ft < 4; ++ft)
            #pragma unroll
            for (int r = 0; r < 4; ++r)
                Ps[16 * wv + 4 * g + r][16 * ft + c] = f2b(s[ft][r]);

        // ---- O += P V : A = Ps rows 16wv.., B = Vt d-blocks
        #pragma unroll
        for (int ks = 0; ks < 2; ++ks) {
            const int kb2 = ks * 32 + g * 8;
            s16x8 pa = *reinterpret_cast<const s16x8*>(&Ps[16 * wv + c][kb2]);
            #pragma unroll
            for (int fd = 0; fd < 4; ++fd) {
                s16x8 bv = *reinterpret_cast<const s16x8*>(&Vt[16 * fd + c][kb2]);
                o[fd] = __builtin_amdgcn_mfma_f32_16x16x32_bf16(pa, bv, o[fd], 0, 0, 0);
            }
        }
    }

    // ---- normalize + store (row q = q0 + 16wv + 4g + r, col d = 16fd + c)
    #pragma unroll
    for (int r = 0; r < 4; ++r) {
        const int row = q0 + 16 * wv + 4 * g + r;
        if (row >= N_) continue;
        const float rinv = 1.f / l[r];
        #pragma unroll
        for (int fd = 0; fd < 4; ++fd)
            qb[(size_t)row * HD + 16 * fd + c] = o[fd][r] * rinv;
    }
}

// ---------------------------------------------------------------------------
// Kernel 3: out = attn_out @ W_proj + bias via bf16 MFMA (UNCHANGED from R11).
// ---------------------------------------------------------------------------
__global__ __launch_bounds__(256) void proj_mfma(
    const float* __restrict__ ao,     // attn out (q buffer), [B,H,N,hd]
    const float* __restrict__ w,      // [768, 768]
    const float* __restrict__ bias,   // [768]
    float* __restrict__ out)          // [M_, 768]
{
    __shared__ unsigned short Al[128][LDB];
    __shared__ unsigned short Bl[128][LDB];

    const int tid  = threadIdx.x;
    const int lane = tid & 63;
    const int wv   = tid >> 6;
    const int wr   = wv >> 1;
    const int wc   = wv & 1;
    const int n0   = blockIdx.x * 128;
    const int m0   = blockIdx.y * 128;

    f32x4 acc[4][4];
    #pragma unroll
    for (int i = 0; i < 4; ++i)
        #pragma unroll
        for (int j = 0; j < 4; ++j)
            acc[i][j] = (f32x4){0.f, 0.f, 0.f, 0.f};

    for (int kt = 0; kt < H_; ++kt) {       // 12 K-tiles = 12 heads
        const int k0 = kt * 64;
        __syncthreads();

        {
            const int row = tid >> 2;
            const int cf4 = tid & 3;
            #pragma unroll
            for (int h2 = 0; h2 < 2; ++h2) {
                const int rr = row + 64 * h2;
                int gm = m0 + rr; if (gm >= M_) gm = M_ - 1;
                const int b   = gm / N_;
                const int tok = gm - b * N_;
                const float* src = ao + (((size_t)b * H_ + kt) * N_ + tok) * HD;
                #pragma unroll
                for (int u = 0; u < 4; ++u) {
                    const int f4 = cf4 + 4 * u;
                    float4 t = *(const float4*)(src + f4 * 4);
                    uint2 pk;
                    pk.x = (unsigned)f2b(t.x) | ((unsigned)f2b(t.y) << 16);
                    pk.y = (unsigned)f2b(t.z) | ((unsigned)f2b(t.w) << 16);
                    *reinterpret_cast<uint2*>(&Al[rr][f4 * 4]) = pk;
                }
            }
        }
        {
            const int kp = tid >> 3;
            const int nb = tid & 7;
            const float* src = w + (size_t)(k0 + 2 * kp) * C_ + n0;
            #pragma unroll
            for (int vv = 0; vv < 4; ++vv) {
                const int f4 = nb + 8 * vv;
                float4 t0 = *(const float4*)(src + f4 * 4);
                float4 t1 = *(const float4*)(src + C_ + f4 * 4);
                #pragma unroll
                for (int c = 0; c < 4; ++c) {
                    unsigned int pr = (unsigned)f2b((&t0.x)[c])
                                    | ((unsigned)f2b((&t1.x)[c]) << 16);
                    *reinterpret_cast<unsigned int*>(&Bl[f4 * 4 + c][2 * kp]) = pr;
                }
            }
        }
        __syncthreads();

        #pragma unroll
        for (int ks = 0; ks < 2; ++ks) {
            const int kb = ks * 32 + (lane >> 4) * 8;
            s16x8 af[4], bf[4];
            #pragma unroll
            for (int fi = 0; fi < 4; ++fi)
                af[fi] = *reinterpret_cast<const s16x8*>(&Al[wr * 64 + fi * 16 + (lane & 15)][kb]);
            #pragma unroll
            for (int fj = 0; fj < 4; ++fj)
                bf[fj] = *reinterpret_cast<const s16x8*>(&Bl[wc * 64 + fj * 16 + (lane & 15)][kb]);
            #pragma unroll
            for (int fi = 0; fi < 4; ++fi)
                #pragma unroll
                for (int fj = 0; fj < 4; ++fj)
                    acc[fi][fj] = __builtin_amdgcn_mfma_f32_16x16x32_bf16(
                        af[fi], bf[fj], acc[fi][fj], 0, 0, 0);
        }
    }

    #pragma unroll
    for (int fj = 0; fj < 4; ++fj) {
        const int gn = n0 + wc * 64 + fj * 16 + (lane & 15);
        const float bv = bias[gn];
        #pragma unroll
        for (int fi = 0; fi < 4; ++fi) {
            #pragma unroll
            for (int r = 0; r < 4; ++r) {
                const int gm = m0 + wr * 64 + fi * 16 + (lane >> 4) * 4 + r;
                if (gm < M_) out[(size_t)gm * C_ + gn] = acc[fi][fj][r] + bv;
            }
        }
    }
}

// ---------------------------------------------------------------------------
extern "C" void kernel_launch(void* const* d_in, const int* in_sizes, int n_in,
                              void* d_out, int out_size, void* d_ws, size_t ws_size,
                              hipStream_t stream) {
    const float* x     = (const float*)d_in[0];
    const float* fcos  = (const float*)d_in[1];
    const float* fsin  = (const float*)d_in[2];
    const float* wqkv  = (const float*)d_in[3];
    const float* wproj = (const float*)d_in[4];
    const float* bproj = (const float*)d_in[5];
    float* out = (float*)d_out;

    const size_t QE = (size_t)B_ * H_ * N_ * HD;   // 12,595,200 elems
    float* q = (float*)d_ws;
    float* k = q + QE;
    float* v = k + QE;
    // ws needed: 3 * QE * 4 B = 151.2 MB (unchanged)

    qkv_mfma<<<dim3(QKVN / 128, (M_ + 127) / 128), 256, 0, stream>>>(
        x, wqkv, fcos, fsin, q, k, v);

    attn_mfma<<<dim3((N_ + 63) / 64, B_ * H_), 256, 0, stream>>>(q, k, v);

    proj_mfma<<<dim3(C_ / 128, (M_ + 127) / 128), 256, 0, stream>>>(
        q, wproj, bproj, out);
}